// Round 2
// baseline (81.637 us; speedup 1.0000x reference)
//
#include <hip/hip_runtime.h>
#include <stdint.h>

#define IN_F   4096
#define OUT_F  11008
#define BATCH  8
#define RPW    4          // output rows per wave
#define WAVES  2          // waves per block
#define RPB    (RPW*WAVES)
#define CHUNK  256        // i-values per wave iteration (64 lanes * 4 elements)

__device__ __forceinline__ float qins_decode(int code, int sgn, float d0, float d1) {
    // |w| = exp2(d0 + code*d1); sign from bit31 of the int32 sign (+1 or -1)
    const float e = __builtin_amdgcn_exp2f(fmaf((float)code, d1, d0));
    const uint32_t m = ((uint32_t)sgn) & 0x80000000u;
    return __uint_as_float(__float_as_uint(e) ^ m);
}

__global__ __launch_bounds__(WAVES*64, 4)
void qins_linear_kernel(const float* __restrict__ x,
                        const int*   __restrict__ stored,
                        const int*   __restrict__ sign,
                        const float* __restrict__ log_min,
                        const float* __restrict__ log_max,
                        const float* __restrict__ bias,
                        float* __restrict__ out)
{
    const int lane = threadIdx.x & 63;
    const int wave = threadIdx.x >> 6;
    const int o0   = blockIdx.x * RPB + wave * RPW;

    const float lmin = log_min[0];
    const float lmax = log_max[0];
    const float L2E  = 1.44269504088896340736f;
    // log2(|w|) = d0 + code*d1
    const float d1 = -(lmax - lmin) * (L2E / 254.0f);
    const float d0 = (lmin + (lmax - lmin) * (255.0f / 254.0f)) * L2E;

    float acc[RPW][BATCH];
#pragma unroll
    for (int r = 0; r < RPW; ++r)
#pragma unroll
        for (int b = 0; b < BATCH; ++b) acc[r][b] = 0.0f;

    const int ii0 = lane * 4;

    for (int i0 = 0; i0 < IN_F; i0 += CHUNK) {
        const int ii = i0 + ii0;

        // x fragments: lane covers 4 consecutive i for all 8 batch rows (L1/L2-hot)
        float4 xr[BATCH];
#pragma unroll
        for (int b = 0; b < BATCH; ++b)
            xr[b] = *reinterpret_cast<const float4*>(x + b * IN_F + ii);

        // coalesced dwordx4 loads: int32 codes + int32 signs for this wave's 4 rows
        int4 sc[RPW], sg[RPW];
#pragma unroll
        for (int r = 0; r < RPW; ++r) {
            const size_t off = (size_t)(o0 + r) * IN_F + ii;
            sc[r] = *reinterpret_cast<const int4*>(stored + off);
            sg[r] = *reinterpret_cast<const int4*>(sign + off);
        }

#pragma unroll
        for (int r = 0; r < RPW; ++r) {
            const float w0 = qins_decode(sc[r].x, sg[r].x, d0, d1);
            const float w1 = qins_decode(sc[r].y, sg[r].y, d0, d1);
            const float w2 = qins_decode(sc[r].z, sg[r].z, d0, d1);
            const float w3 = qins_decode(sc[r].w, sg[r].w, d0, d1);
#pragma unroll
            for (int b = 0; b < BATCH; ++b) {
                float a = acc[r][b];
                a = fmaf(w0, xr[b].x, a);
                a = fmaf(w1, xr[b].y, a);
                a = fmaf(w2, xr[b].z, a);
                a = fmaf(w3, xr[b].w, a);
                acc[r][b] = a;
            }
        }
    }

    // full-wave butterfly reduction for the 32 (row,batch) partials
#pragma unroll
    for (int r = 0; r < RPW; ++r)
#pragma unroll
        for (int b = 0; b < BATCH; ++b) {
            float v = acc[r][b];
#pragma unroll
            for (int s = 32; s >= 1; s >>= 1)
                v += __shfl_xor(v, s, 64);
            acc[r][b] = v;
        }

    if (lane == 0) {
#pragma unroll
        for (int r = 0; r < RPW; ++r) {
            const float bv = bias[o0 + r];
#pragma unroll
            for (int b = 0; b < BATCH; ++b)
                out[(size_t)b * OUT_F + o0 + r] = acc[r][b] + bv;
        }
    }
}

extern "C" void kernel_launch(void* const* d_in, const int* in_sizes, int n_in,
                              void* d_out, int out_size, void* d_ws, size_t ws_size,
                              hipStream_t stream)
{
    const float* x      = (const float*)d_in[0];
    const int*   stored = (const int*)d_in[1];
    const int*   sign   = (const int*)d_in[2];
    const float* lmin   = (const float*)d_in[3];
    const float* lmax   = (const float*)d_in[4];
    const float* bias   = (const float*)d_in[5];
    float* out = (float*)d_out;

    dim3 grid(OUT_F / RPB), block(WAVES * 64);
    qins_linear_kernel<<<grid, block, 0, stream>>>(x, stored, sign, lmin, lmax, bias, out);
}